// Round 1
// 865.908 us; speedup vs baseline: 2.6436x; 2.6436x over previous
//
#include <hip/hip_runtime.h>

#define NB 2
#define NN 1024
#define HID 512
#define NHD 8
#define HD 64
#define NE 16

// ---- K0: mask dtype detection: 0=int32, 1=uint8-packed, 2=fp32, 3=int64 ----
__global__ __launch_bounds__(256) void k_maskdet(const unsigned int* __restrict__ m,
                                                 int* __restrict__ flag) {
    __shared__ int sh;
    if (threadIdx.x == 0) sh = 0;
    __syncthreads();
    int loc = 0;
    for (int i = threadIdx.x; i < 4096; i += 256) {  // 16 KB prefix, in-bounds for all encodings
        unsigned v = m[i];
        if (v == 0x3F800000u) loc |= 1;              // fp32 1.0 marker
        else if (v > 1u) loc |= 2;                   // packed-byte marker
        else if (v != 0u) loc |= (i & 1) ? 4 : 8;    // nonzero at odd / even word index
    }
    if (loc) atomicOr(&sh, loc);
    __syncthreads();
    if (threadIdx.x == 0) {
        int s = sh;
        int mode;
        if (s & 1) mode = 2;                          // fp32
        else if (s & 2) mode = 1;                     // uint8
        else if ((s & 8) && !(s & 4)) mode = 3;       // int64: ones only in (even) low words
        else mode = 0;                                // int32
        *flag = mode;
    }
}

__device__ __forceinline__ float eluf(float x) {
    return x > 0.f ? x : (__expf(x) - 1.f);
}

// ---- K1: edge-MLP bias + mask -> attn buffer as (b,h,q,k) planes ----------
// Layer-1 (16x16) computed ONCE per (b,q,k) and shared across all 8 heads.
// Masked entries get -1e30. 2 pairs per thread; block covers 512 k of one (b,q) row.
__global__ __launch_bounds__(256) void k_bias(
    const float* __restrict__ ef,
    const float* __restrict__ We1, const float* __restrict__ be1,
    const float* __restrict__ We2, const float* __restrict__ be2,
    const void* __restrict__ mask, const int* __restrict__ mode_p,
    float* __restrict__ attn) {
    __shared__ __align__(16) float w1[16][16];   // [f][o]
    __shared__ __align__(16) float w2[16][8];    // [o][h]
    __shared__ __align__(16) float b1s[16];
    __shared__ __align__(16) float b2s[8];
    int tid = threadIdx.x;
    w1[tid >> 4][tid & 15] = We1[tid];
    if (tid < 128) w2[tid >> 3][tid & 7] = We2[tid];
    if (tid < 16) b1s[tid] = be1[tid];
    if (tid < 8)  b2s[tid] = be2[tid];
    __syncthreads();
    int mode = *mode_p;
    int rowid = blockIdx.x >> 1;        // b*NN + q
    int kh = blockIdx.x & 1;            // which half of the k range
    int b = rowid >> 10, q = rowid & 1023;
    const float* erow = ef + (size_t)rowid * NN * NE;
    size_t mbase = (size_t)rowid * NN;
    int k0 = kh * 512 + tid;            // pair0: k0, pair1: k0+256  (coalesced)

    float e0[16], e1[16];
    {
        const float* p0 = erow + (size_t)k0 * NE;
        const float* p1 = erow + (size_t)(k0 + 256) * NE;
#pragma unroll
        for (int c = 0; c < 4; c++) {
            float4 v0 = *(const float4*)(p0 + c * 4);
            float4 v1 = *(const float4*)(p1 + c * 4);
            e0[4*c+0] = v0.x; e0[4*c+1] = v0.y; e0[4*c+2] = v0.z; e0[4*c+3] = v0.w;
            e1[4*c+0] = v1.x; e1[4*c+1] = v1.y; e1[4*c+2] = v1.z; e1[4*c+3] = v1.w;
        }
    }
    // layer 1: h = e @ We1 + b1   (float4 LDS reads, shared across both pairs)
    float4 h0[4], h1[4];
#pragma unroll
    for (int c = 0; c < 4; c++) {
        float4 bb = *(const float4*)(&b1s[c * 4]);
        h0[c] = bb; h1[c] = bb;
    }
#pragma unroll
    for (int f = 0; f < 16; f++) {
#pragma unroll
        for (int c = 0; c < 4; c++) {
            float4 wr = *(const float4*)(&w1[f][c * 4]);
            h0[c].x += e0[f] * wr.x; h0[c].y += e0[f] * wr.y;
            h0[c].z += e0[f] * wr.z; h0[c].w += e0[f] * wr.w;
            h1[c].x += e1[f] * wr.x; h1[c].y += e1[f] * wr.y;
            h1[c].z += e1[f] * wr.z; h1[c].w += e1[f] * wr.w;
        }
    }
    // ELU
    float g0[16], g1[16];
#pragma unroll
    for (int c = 0; c < 4; c++) {
        g0[4*c+0] = eluf(h0[c].x); g0[4*c+1] = eluf(h0[c].y);
        g0[4*c+2] = eluf(h0[c].z); g0[4*c+3] = eluf(h0[c].w);
        g1[4*c+0] = eluf(h1[c].x); g1[4*c+1] = eluf(h1[c].y);
        g1[4*c+2] = eluf(h1[c].z); g1[4*c+3] = eluf(h1[c].w);
    }
    // layer 2: all 8 heads at once
    float4 o0a = *(const float4*)(&b2s[0]);
    float4 o0b = *(const float4*)(&b2s[4]);
    float4 o1a = o0a, o1b = o0b;
#pragma unroll
    for (int o = 0; o < 16; o++) {
        float4 wa = *(const float4*)(&w2[o][0]);
        float4 wb = *(const float4*)(&w2[o][4]);
        o0a.x += g0[o] * wa.x; o0a.y += g0[o] * wa.y; o0a.z += g0[o] * wa.z; o0a.w += g0[o] * wa.w;
        o0b.x += g0[o] * wb.x; o0b.y += g0[o] * wb.y; o0b.z += g0[o] * wb.z; o0b.w += g0[o] * wb.w;
        o1a.x += g1[o] * wa.x; o1a.y += g1[o] * wa.y; o1a.z += g1[o] * wa.z; o1a.w += g1[o] * wa.w;
        o1b.x += g1[o] * wb.x; o1b.y += g1[o] * wb.y; o1b.z += g1[o] * wb.z; o1b.w += g1[o] * wb.w;
    }
    // mask
    size_t p0i = mbase + k0, p1i = mbase + k0 + 256;
    bool m0, m1;
    if (mode == 3) {
        m0 = ((const unsigned int*)mask)[2 * p0i] != 0u;
        m1 = ((const unsigned int*)mask)[2 * p1i] != 0u;
    } else if (mode == 2) {
        m0 = ((const float*)mask)[p0i] != 0.0f;
        m1 = ((const float*)mask)[p1i] != 0.0f;
    } else if (mode == 1) {
        m0 = ((const unsigned char*)mask)[p0i] != 0;
        m1 = ((const unsigned char*)mask)[p1i] != 0;
    } else {
        m0 = ((const int*)mask)[p0i] != 0;
        m1 = ((const int*)mask)[p1i] != 0;
    }
    float r0v[8] = {o0a.x, o0a.y, o0a.z, o0a.w, o0b.x, o0b.y, o0b.z, o0b.w};
    float r1v[8] = {o1a.x, o1a.y, o1a.z, o1a.w, o1b.x, o1b.y, o1b.z, o1b.w};
#pragma unroll
    for (int hh = 0; hh < 8; hh++) {
        size_t base = ((size_t)(b * NHD + hh) * NN + q) * NN;
        attn[base + k0]       = m0 ? -1e30f : r0v[hh];
        attn[base + k0 + 256] = m1 ? -1e30f : r1v[hh];
    }
}

// ---- tiled 64x64 GEMM core: X(2048x512) @ W(512x512), 4x4 per thread ------
__device__ __forceinline__ void gemm_tile_512(
    const float* __restrict__ X, const float* __restrict__ W,
    int m0, int n0, float* xs, float4 acc[4]) {
    int tid = threadIdx.x;
    int tn = tid & 15, tm = tid >> 4;
    acc[0] = make_float4(0.f, 0.f, 0.f, 0.f);
    acc[1] = acc[0]; acc[2] = acc[0]; acc[3] = acc[0];
    for (int kc = 0; kc < 512; kc += 64) {
        __syncthreads();
#pragma unroll
        for (int j = 0; j < 4; j++) {
            int ml = tm + 16 * j;
            *(float4*)(xs + ml * 64 + tn * 4) =
                *(const float4*)(X + (size_t)(m0 + ml) * 512 + kc + tn * 4);
        }
        __syncthreads();
#pragma unroll 4
        for (int k4 = 0; k4 < 16; k4++) {
            float4 x0 = *(const float4*)(xs + (tm * 4 + 0) * 64 + k4 * 4);
            float4 x1 = *(const float4*)(xs + (tm * 4 + 1) * 64 + k4 * 4);
            float4 x2 = *(const float4*)(xs + (tm * 4 + 2) * 64 + k4 * 4);
            float4 x3 = *(const float4*)(xs + (tm * 4 + 3) * 64 + k4 * 4);
            const float* wr = W + (size_t)(kc + k4 * 4) * 512 + n0 + tn * 4;
#pragma unroll
            for (int kk = 0; kk < 4; kk++) {
                float4 w = *(const float4*)(wr + (size_t)kk * 512);
                float a0 = (kk == 0) ? x0.x : (kk == 1) ? x0.y : (kk == 2) ? x0.z : x0.w;
                float a1 = (kk == 0) ? x1.x : (kk == 1) ? x1.y : (kk == 2) ? x1.z : x1.w;
                float a2 = (kk == 0) ? x2.x : (kk == 1) ? x2.y : (kk == 2) ? x2.z : x2.w;
                float a3 = (kk == 0) ? x3.x : (kk == 1) ? x3.y : (kk == 2) ? x3.z : x3.w;
                acc[0].x += a0 * w.x; acc[0].y += a0 * w.y; acc[0].z += a0 * w.z; acc[0].w += a0 * w.w;
                acc[1].x += a1 * w.x; acc[1].y += a1 * w.y; acc[1].z += a1 * w.z; acc[1].w += a1 * w.w;
                acc[2].x += a2 * w.x; acc[2].y += a2 * w.y; acc[2].z += a2 * w.z; acc[2].w += a2 * w.w;
                acc[3].x += a3 * w.x; acc[3].y += a3 * w.y; acc[3].z += a3 * w.z; acc[3].w += a3 * w.w;
            }
        }
    }
}

// ---- K2: QKV projections, tiled; all outputs in (b,h,tok,d) layout --------
__global__ __launch_bounds__(256) void k_qkv_t(
    const float* __restrict__ x,
    const float* __restrict__ Wq, const float* __restrict__ Wk, const float* __restrict__ Wv,
    const float* __restrict__ bq, const float* __restrict__ bk, const float* __restrict__ bv,
    float* __restrict__ qb, float* __restrict__ kb, float* __restrict__ vb) {
    __shared__ __align__(16) float xs[64 * 64];
    int bx = blockIdx.x;
    int which = bx >> 8; bx &= 255;
    int m0 = (bx >> 3) * 64, n0 = (bx & 7) * 64;
    const float* W    = (which == 0) ? Wq : (which == 1) ? Wk : Wv;
    const float* bias = (which == 0) ? bq : (which == 1) ? bk : bv;
    float* out        = (which == 0) ? qb : (which == 1) ? kb : vb;
    float4 acc[4];
    gemm_tile_512(x, W, m0, n0, xs, acc);
    int tn = threadIdx.x & 15, tm = threadIdx.x >> 4;
    float4 bv4 = *(const float4*)(bias + n0 + tn * 4);
    int hh = n0 >> 6, d = tn * 4;        // n0 is 64-aligned -> single head per tile
#pragma unroll
    for (int r = 0; r < 4; r++) {
        int m = m0 + tm * 4 + r;
        int b = m >> 10, tok = m & 1023;
        float4 v = acc[r];
        v.x += bv4.x; v.y += bv4.y; v.z += bv4.z; v.w += bv4.w;
        *(float4*)(out + (((size_t)(b * NHD + hh) * NN + tok) * HD + d)) = v;
    }
}

// ---- K3: QK^T + bias(in attn buf) + softmax -> attn -----------------------
// Block: one (b,h), 8 q-rows (2 per wave). K staged in LDS tiles of 128 rows,
// 16B-chunk XOR swizzle (c ^= r&15) -> conflict-free ds_read_b128.
__global__ __launch_bounds__(256) void k_escore2(
    const float* __restrict__ qb, const float* __restrict__ kb,
    float* __restrict__ attn) {
    __shared__ __align__(16) float ks[128 * 64];  // 32 KB
    int bx = blockIdx.x;
    int bh = bx >> 7;
    int q0 = (bx & 127) * 8;
    int tid = threadIdx.x;
    int lane = tid & 63, wv = tid >> 6;
    const float* kbh = kb + (size_t)bh * (NN * HD);
    int qr0 = q0 + wv * 2, qr1 = qr0 + 1;
    const float* qrow0 = qb + ((size_t)bh * NN + qr0) * HD;
    const float* qrow1 = qb + ((size_t)bh * NN + qr1) * HD;
    float4 qv0[16], qv1[16];
#pragma unroll
    for (int c = 0; c < 16; c++) {
        qv0[c] = *(const float4*)(qrow0 + c * 4);
        qv1[c] = *(const float4*)(qrow1 + c * 4);
    }
    float s0[16], s1[16];
    int sw = lane & 15;
#pragma unroll
    for (int t = 0; t < 8; t++) {
        __syncthreads();
        // stage tile: LDS linear, global source pre-swizzled (chunk c' holds chunk c'^ (r&15))
#pragma unroll
        for (int it = 0; it < 8; it++) {
            int s = tid + 256 * it;
            int r = s >> 4;
            int c = (s & 15) ^ (r & 15);
            *(float4*)(ks + s * 4) =
                *(const float4*)(kbh + (size_t)(t * 128 + r) * HD + c * 4);
        }
        __syncthreads();
#pragma unroll
        for (int j = 0; j < 2; j++) {
            int kr = lane + 64 * j;
            const float* krow = ks + kr * 64;
            float4 a0 = make_float4(0.f, 0.f, 0.f, 0.f);
            float4 a1 = a0;
#pragma unroll
            for (int c = 0; c < 16; c++) {
                float4 kv = *(const float4*)(krow + ((c ^ sw) * 4));
                a0.x += qv0[c].x * kv.x; a0.y += qv0[c].y * kv.y;
                a0.z += qv0[c].z * kv.z; a0.w += qv0[c].w * kv.w;
                a1.x += qv1[c].x * kv.x; a1.y += qv1[c].y * kv.y;
                a1.z += qv1[c].z * kv.z; a1.w += qv1[c].w * kv.w;
            }
            s0[2 * t + j] = (a0.x + a0.y) + (a0.z + a0.w);
            s1[2 * t + j] = (a1.x + a1.y) + (a1.z + a1.w);
        }
    }
    size_t row0 = ((size_t)bh * NN + qr0) * NN;
    size_t row1 = ((size_t)bh * NN + qr1) * NN;
    float mx0 = -3e38f, mx1 = -3e38f;
#pragma unroll
    for (int i = 0; i < 16; i++) {
        float b0 = attn[row0 + lane + 64 * i];
        float b1 = attn[row1 + lane + 64 * i];
        s0[i] = fmaf(s0[i], 0.125f, b0);
        s1[i] = fmaf(s1[i], 0.125f, b1);
        mx0 = fmaxf(mx0, s0[i]);
        mx1 = fmaxf(mx1, s1[i]);
    }
#pragma unroll
    for (int off = 1; off < 64; off <<= 1) {
        mx0 = fmaxf(mx0, __shfl_xor(mx0, off));
        mx1 = fmaxf(mx1, __shfl_xor(mx1, off));
    }
    float sum0 = 0.f, sum1 = 0.f;
#pragma unroll
    for (int i = 0; i < 16; i++) {
        float p0 = (s0[i] < -1e29f) ? 0.f : __expf(s0[i] - mx0);
        float p1 = (s1[i] < -1e29f) ? 0.f : __expf(s1[i] - mx1);
        s0[i] = p0; s1[i] = p1;
        sum0 += p0; sum1 += p1;
    }
#pragma unroll
    for (int off = 1; off < 64; off <<= 1) {
        sum0 += __shfl_xor(sum0, off);
        sum1 += __shfl_xor(sum1, off);
    }
    float inv0 = (sum0 > 0.f) ? 1.f / sum0 : 0.f;
    float inv1 = (sum1 > 0.f) ? 1.f / sum1 : 0.f;
#pragma unroll
    for (int i = 0; i < 16; i++) {
        attn[row0 + lane + 64 * i] = s0[i] * inv0;
        attn[row1 + lane + 64 * i] = s1[i] * inv1;
    }
}

// ---- K4: attn @ V -> oattn.  Wave per (b,h, 8 q-rows), lane = d. ----------
__global__ __launch_bounds__(256) void k_av2(
    const float* __restrict__ attn, const float* __restrict__ vb,
    float* __restrict__ oattn) {
    int w = blockIdx.x * 4 + (threadIdx.x >> 6);
    int lane = threadIdx.x & 63;
    int bh = w >> 7;
    int q0 = (w & 127) * 8;
    const float* ar = attn + ((size_t)bh * NN + q0) * NN;
    const float* vbh = vb + (size_t)bh * (NN * HD);
    float acc[8] = {0.f, 0.f, 0.f, 0.f, 0.f, 0.f, 0.f, 0.f};
#pragma unroll 2
    for (int k = 0; k < NN; k += 4) {
        float4 a[8];
#pragma unroll
        for (int r = 0; r < 8; r++) a[r] = *(const float4*)(ar + (size_t)r * NN + k);
        float v0 = vbh[(k + 0) * HD + lane];
        float v1 = vbh[(k + 1) * HD + lane];
        float v2 = vbh[(k + 2) * HD + lane];
        float v3 = vbh[(k + 3) * HD + lane];
#pragma unroll
        for (int r = 0; r < 8; r++) {
            acc[r] += a[r].x * v0;
            acc[r] += a[r].y * v1;
            acc[r] += a[r].z * v2;
            acc[r] += a[r].w * v3;
        }
    }
    int b = bh >> 3, hh = bh & 7;
#pragma unroll
    for (int r = 0; r < 8; r++)
        oattn[(size_t)(b * NN + q0 + r) * HID + hh * 64 + lane] = acc[r];
}

// ---- K5: output projection, tiled --------------------------------------
__global__ __launch_bounds__(256) void k_oproj_t(
    const float* __restrict__ oa, const float* __restrict__ Wo,
    const float* __restrict__ bo, float* __restrict__ out) {
    __shared__ __align__(16) float xs[64 * 64];
    int bx = blockIdx.x;
    int m0 = (bx >> 3) * 64, n0 = (bx & 7) * 64;
    float4 acc[4];
    gemm_tile_512(oa, Wo, m0, n0, xs, acc);
    int tn = threadIdx.x & 15, tm = threadIdx.x >> 4;
    float4 bv4 = *(const float4*)(bo + n0 + tn * 4);
#pragma unroll
    for (int r = 0; r < 4; r++) {
        int m = m0 + tm * 4 + r;
        float4 v = acc[r];
        v.x += bv4.x; v.y += bv4.y; v.z += bv4.z; v.w += bv4.w;
        *(float4*)(out + (size_t)m * HID + n0 + tn * 4) = v;
    }
}

extern "C" void kernel_launch(void* const* d_in, const int* in_sizes, int n_in,
                              void* d_out, int out_size, void* d_ws, size_t ws_size,
                              hipStream_t stream) {
    (void)in_sizes; (void)n_in; (void)out_size; (void)ws_size;
    const float* x   = (const float*)d_in[0];
    const float* ef  = (const float*)d_in[1];
    const void*  msk = d_in[2];
    const float* Wq  = (const float*)d_in[3];
    const float* bq  = (const float*)d_in[4];
    const float* Wk  = (const float*)d_in[5];
    const float* bk  = (const float*)d_in[6];
    const float* Wv  = (const float*)d_in[7];
    const float* bv  = (const float*)d_in[8];
    const float* Wo  = (const float*)d_in[9];
    const float* bo  = (const float*)d_in[10];
    const float* We1 = (const float*)d_in[11];
    const float* be1 = (const float*)d_in[12];
    const float* We2 = (const float*)d_in[13];
    const float* be2 = (const float*)d_in[14];

    char* ws = (char*)d_ws;
    float* qb    = (float*)(ws + 0);          // 4 MB  (b,h,tok,d)
    float* kb    = (float*)(ws + 4194304);    // 4 MB  (b,h,tok,d)
    float* vb    = (float*)(ws + 8388608);    // 4 MB  (b,h,tok,d)
    float* oattn = (float*)(ws + 12582912);   // 4 MB  (b,tok, h*64+d)
    int*   flag  = (int*)(ws + 16777216);     // 4 B

    float* out0 = (float*)d_out;
    float* attn = out0 + (size_t)NB * NN * HID;  // output 1: (B,H,N,N) fp32

    k_maskdet<<<1, 256, 0, stream>>>((const unsigned int*)msk, flag);
    k_bias<<<NB * NN * 2, 256, 0, stream>>>(ef, We1, be1, We2, be2, msk, flag, attn);
    k_qkv_t<<<768, 256, 0, stream>>>(x, Wq, Wk, Wv, bq, bk, bv, qb, kb, vb);
    k_escore2<<<2048, 256, 0, stream>>>(qb, kb, attn);
    k_av2<<<512, 256, 0, stream>>>(attn, vb, oattn);
    k_oproj_t<<<256, 256, 0, stream>>>(oattn, Wo, bo, out0);
}